// Round 2
// baseline (335.032 us; speedup 1.0000x reference)
//
#include <hip/hip_runtime.h>
#include <math.h>

#define BATCH_N   32768
#define IN_F      784
#define HID_F     256
#define NCLS      10
#define BM        32          // batch rows per block
#define KT        28          // K tile: 784 = 28*28
#define NKT       (IN_F / KT) // 28 tiles
#define NTHREADS  256

// Fused MLP: hidden = relu(x @ W1^T + b1); out = softmax(hidden @ W2^T + b2)
// R1 -> R2 change: x is wave-uniform (8 rows per wave, all 64 lanes use the
// same values) so it is loaded via readfirstlane-uniform global loads
// (scalar-load / L1-broadcast path) instead of round-tripping through LDS.
// LDS now carries only the W1 tile: 4 ds_read_b128 per k-group per lane
// = 0.5 B/FMA, under the ~1 B/FMA LDS-pipe budget. R1 was LDS-bound at
// 1.5 B/FMA (12 reads/kg) -> 232us vs 84us FMA floor.
__global__ __launch_bounds__(NTHREADS, 4)
void mlp_fused_kernel(const float* __restrict__ x,
                      const float* __restrict__ w1,
                      const float* __restrict__ b1,
                      const float* __restrict__ w2,
                      const float* __restrict__ b2,
                      float* __restrict__ out)
{
    __shared__ float smem[BM * HID_F];      // 32 KB union
    float* ws  = smem;                      // [KT][HID_F] phase 1: W1 tile, transposed (28 KB)
    float* hid = smem;                      // [BM][HID_F] phase 2: hidden (32 KB)

    const int tid  = threadIdx.x;
    const int wave = tid >> 6;
    const int lane = tid & 63;
    const int row0 = blockIdx.x * BM;       // global batch row base
    const int r0   = wave * 8;              // this wave's local rows: r0..r0+7
    const int c0   = lane * 4;              // this lane's hidden cols: c0..c0+3

    // Wave-uniform x row base; readfirstlane tells the backend it's uniform
    // so x loads can scalarize (s_load) or at least broadcast through L1.
    const int urow = __builtin_amdgcn_readfirstlane(row0 + r0);
    const float* xw = x + (size_t)urow * IN_F;

    float acc[8][4];
    #pragma unroll
    for (int r = 0; r < 8; ++r)
        #pragma unroll
        for (int c = 0; c < 4; ++c) acc[r][c] = 0.f;

    for (int kt = 0; kt < NKT; ++kt) {
        const int k0 = kt * KT;
        __syncthreads();   // protect ws from previous iteration's readers

        // stage W1 tile transposed: thread tid = hidden col, 7 float4 along k.
        // LDS writes are stride-1 across tid -> conflict-free.
        {
            const float* src = w1 + (size_t)tid * IN_F + k0;
            #pragma unroll
            for (int f = 0; f < KT / 4; ++f) {
                const float4 v = *(const float4*)(src + 4 * f);
                ws[(4 * f + 0) * HID_F + tid] = v.x;
                ws[(4 * f + 1) * HID_F + tid] = v.y;
                ws[(4 * f + 2) * HID_F + tid] = v.z;
                ws[(4 * f + 3) * HID_F + tid] = v.w;
            }
        }
        __syncthreads();

        // compute: per lane 8 rows x 4 cols, k in groups of 4.
        // x comes from uniform global loads (no LDS); W from LDS b128.
        #pragma unroll
        for (int kg = 0; kg < KT / 4; ++kg) {
            float4 w4[4];
            #pragma unroll
            for (int kk = 0; kk < 4; ++kk)      // cols c0..c0+3 for k = 4kg+kk
                w4[kk] = *(const float4*)&ws[(4 * kg + kk) * HID_F + c0];
            #pragma unroll
            for (int r = 0; r < 8; ++r) {
                const float4 xv = *(const float4*)(xw + r * IN_F + k0 + 4 * kg);
                acc[r][0] += xv.x * w4[0].x; acc[r][1] += xv.x * w4[0].y;
                acc[r][2] += xv.x * w4[0].z; acc[r][3] += xv.x * w4[0].w;
                acc[r][0] += xv.y * w4[1].x; acc[r][1] += xv.y * w4[1].y;
                acc[r][2] += xv.y * w4[1].z; acc[r][3] += xv.y * w4[1].w;
                acc[r][0] += xv.z * w4[2].x; acc[r][1] += xv.z * w4[2].y;
                acc[r][2] += xv.z * w4[2].z; acc[r][3] += xv.z * w4[2].w;
                acc[r][0] += xv.w * w4[3].x; acc[r][1] += xv.w * w4[3].y;
                acc[r][2] += xv.w * w4[3].z; acc[r][3] += xv.w * w4[3].w;
            }
        }
    }

    __syncthreads();   // ws dead; reuse LDS as hidden[32][256]
    {
        const float4 bv = *(const float4*)(b1 + c0);
        #pragma unroll
        for (int r = 0; r < 8; ++r) {
            float4 h;
            h.x = fmaxf(acc[r][0] + bv.x, 0.f);
            h.y = fmaxf(acc[r][1] + bv.y, 0.f);
            h.z = fmaxf(acc[r][2] + bv.z, 0.f);
            h.w = fmaxf(acc[r][3] + bv.w, 0.f);
            *(float4*)&hid[(r0 + r) * HID_F + c0] = h;
        }
    }
    __syncthreads();

    // phase 2: lane l -> row r0 + l/8, h-slice j = l%8 covers h in [32j, 32j+32)
    const int r = r0 + (lane >> 3);
    const int j = lane & 7;
    float lg[NCLS];
    #pragma unroll
    for (int c = 0; c < NCLS; ++c) lg[c] = 0.f;
    const float* hrow = &hid[r * HID_F + j * 32];
    #pragma unroll
    for (int i = 0; i < 8; ++i) {
        const float4 hv = *(const float4*)&hrow[4 * i];
        #pragma unroll
        for (int c = 0; c < NCLS; ++c) {
            const float4 wv = *(const float4*)(w2 + c * HID_F + j * 32 + 4 * i); // L1/L2-hot (10KB)
            lg[c] += hv.x * wv.x + hv.y * wv.y + hv.z * wv.z + hv.w * wv.w;
        }
    }
    // reduce the 8 h-slices (lanes j=0..7 within each 8-lane group share r)
    #pragma unroll
    for (int c = 0; c < NCLS; ++c) {
        float v = lg[c];
        v += __shfl_xor(v, 1);
        v += __shfl_xor(v, 2);
        v += __shfl_xor(v, 4);
        lg[c] = v;
    }
    if (j == 0) {
        float mx = -1e30f;
        #pragma unroll
        for (int c = 0; c < NCLS; ++c) { lg[c] += b2[c]; mx = fmaxf(mx, lg[c]); }
        float s = 0.f;
        #pragma unroll
        for (int c = 0; c < NCLS; ++c) { lg[c] = __expf(lg[c] - mx); s += lg[c]; }
        const float inv = 1.f / s;
        float* o = out + (size_t)(row0 + r) * NCLS;
        #pragma unroll
        for (int c = 0; c < NCLS; ++c) o[c] = lg[c] * inv;
    }
}

extern "C" void kernel_launch(void* const* d_in, const int* in_sizes, int n_in,
                              void* d_out, int out_size, void* d_ws, size_t ws_size,
                              hipStream_t stream)
{
    const float* x  = (const float*)d_in[0];
    const float* w1 = (const float*)d_in[1];
    const float* b1 = (const float*)d_in[2];
    const float* w2 = (const float*)d_in[3];
    const float* b2 = (const float*)d_in[4];
    float* out = (float*)d_out;

    dim3 grid(BATCH_N / BM);   // 1024 blocks, exact
    dim3 block(NTHREADS);
    hipLaunchKernelGGL(mlp_fused_kernel, grid, block, 0, stream,
                       x, w1, b1, w2, b2, out);
}

// Round 4
// 281.648 us; speedup vs baseline: 1.1895x; 1.1895x over previous
//
#include <hip/hip_runtime.h>
#include <math.h>

#define BATCH_N   32768
#define IN_F      784
#define HID_F     256
#define NCLS      10
#define BM        64          // batch rows per block
#define BK        32          // K per MFMA step / per staging tile
#define NKT       25          // ceil(784/32): last tile zero-padded to k=800
#define NTHREADS  256

typedef __attribute__((ext_vector_type(8))) short short8;  // 8 bf16 (guide-verified frag type)
typedef __attribute__((ext_vector_type(4))) float f32x4;

// LDS (64 KB exactly, 2 blocks/CU):
//  phase 1 (staging, frag-image layout: lane-linear 16B slots -> conflict-free b128):
//    AH[4 rt][64 lanes][16B] = 4 KB   | AL = 4 KB
//    BH[16 ct][64 lanes][16B] = 16 KB | BL = 16 KB     total 40 KB
//  phase 2: hid[64][256] f32, XOR-swizzled (col ^ ((row&7)<<2)) = 64 KB
#define AH_OFF 0
#define AL_OFF 4096
#define BH_OFF 8192
#define BL_OFF 24576
#define LDS_BYTES 65536

// fp32 -> split bf16 (hi = truncate, lo = exact residual truncated), pack 4+4 shorts
__device__ __forceinline__ void cvt_store(char* hi_p, char* lo_p, float4 v) {
    unsigned bx = __float_as_uint(v.x), by = __float_as_uint(v.y),
             bz = __float_as_uint(v.z), bw = __float_as_uint(v.w);
    float lx = v.x - __uint_as_float(bx & 0xFFFF0000u);   // exact (Sterbenz)
    float ly = v.y - __uint_as_float(by & 0xFFFF0000u);
    float lz = v.z - __uint_as_float(bz & 0xFFFF0000u);
    float lw = v.w - __uint_as_float(bw & 0xFFFF0000u);
    uint2 hv, lv;
    hv.x = (bx >> 16) | (by & 0xFFFF0000u);
    hv.y = (bz >> 16) | (bw & 0xFFFF0000u);
    lv.x = (__float_as_uint(lx) >> 16) | (__float_as_uint(ly) & 0xFFFF0000u);
    lv.y = (__float_as_uint(lz) >> 16) | (__float_as_uint(lw) & 0xFFFF0000u);
    *(uint2*)hi_p = hv;
    *(uint2*)lo_p = lv;
}

__global__ __launch_bounds__(NTHREADS, 2)
void mlp_mfma_kernel(const float* __restrict__ x,
                     const float* __restrict__ w1,
                     const float* __restrict__ b1,
                     const float* __restrict__ w2,
                     const float* __restrict__ b2,
                     float* __restrict__ out)
{
    __shared__ f32x4 smemv[LDS_BYTES / 16];
    char* lds = (char*)smemv;

    const int tid  = threadIdx.x;
    const int wv   = tid >> 6;          // wave 0..3: owns col-tiles ct = 4wv..4wv+3
    const int lane = tid & 63;
    const int m    = lane & 15;
    const int quad = lane >> 4;
    const int row0 = blockIdx.x * BM;

    f32x4 acc[4][4];                    // [row-tile][col-tile] of 16x16 fp32
    #pragma unroll
    for (int a = 0; a < 4; ++a)
        #pragma unroll
        for (int b = 0; b < 4; ++b)
            acc[a][b] = (f32x4){0.f, 0.f, 0.f, 0.f};

    #pragma unroll 1
    for (int kt = 0; kt < NKT; ++kt) {
        const int kb = kt * BK;
        __syncthreads();                // protect staging LDS from prior readers

        // ---- stage x tile 64x32 fp32 -> AH/AL frag images (512 float4) ----
        #pragma unroll
        for (int p = 0; p < 2; ++p) {
            const int idx = tid + NTHREADS * p;
            const int r = idx >> 3, f = idx & 7;     // 8 float4 per row
            const int k = kb + 4 * f;
            float4 v = make_float4(0.f, 0.f, 0.f, 0.f);
            if (k < IN_F) v = *(const float4*)(x + (size_t)(row0 + r) * IN_F + k);
            // element (r,k): rt=r>>4, m=r&15, quad=k>>3=f>>1, j0=(f&1)*4
            const int off = ((r >> 4) << 10) + (((f >> 1) * 16 + (r & 15)) << 4) + ((f & 1) << 3);
            cvt_store(lds + AH_OFF + off, lds + AL_OFF + off, v);
        }
        // ---- stage w1 tile 256x32 fp32 -> BH/BL frag images (2048 float4) ----
        #pragma unroll
        for (int p = 0; p < 8; ++p) {
            const int idx = tid + NTHREADS * p;
            const int n = idx >> 3, f = idx & 7;
            const int k = kb + 4 * f;
            float4 v = make_float4(0.f, 0.f, 0.f, 0.f);
            if (k < IN_F) v = *(const float4*)(w1 + (size_t)n * IN_F + k);
            const int off = ((n >> 4) << 10) + (((f >> 1) * 16 + (n & 15)) << 4) + ((f & 1) << 3);
            cvt_store(lds + BH_OFF + off, lds + BL_OFF + off, v);
        }
        __syncthreads();

        // ---- fragment reads: lane-linear b128, conflict-free ----
        short8 ah[4], al[4], bh[4], bl[4];
        #pragma unroll
        for (int t = 0; t < 4; ++t) {
            ah[t] = *(const short8*)(lds + AH_OFF + (t << 10) + (lane << 4));
            al[t] = *(const short8*)(lds + AL_OFF + (t << 10) + (lane << 4));
            bh[t] = *(const short8*)(lds + BH_OFF + ((wv * 4 + t) << 10) + (lane << 4));
            bl[t] = *(const short8*)(lds + BL_OFF + ((wv * 4 + t) << 10) + (lane << 4));
        }
        // ---- 3-product split-bf16 MFMA: hi*hi + lo*hi + hi*lo ----
        #pragma unroll
        for (int rt = 0; rt < 4; ++rt)
            #pragma unroll
            for (int c = 0; c < 4; ++c) {
                acc[rt][c] = __builtin_amdgcn_mfma_f32_16x16x32_bf16(ah[rt], bh[c], acc[rt][c], 0, 0, 0);
                acc[rt][c] = __builtin_amdgcn_mfma_f32_16x16x32_bf16(al[rt], bh[c], acc[rt][c], 0, 0, 0);
                acc[rt][c] = __builtin_amdgcn_mfma_f32_16x16x32_bf16(ah[rt], bl[c], acc[rt][c], 0, 0, 0);
            }
    }

    // ---- epilogue layer 1: bias + relu -> hid in LDS (XOR-swizzled) ----
    __syncthreads();                    // staging buffers dead
    float* hid = (float*)lds;           // [64][256], addr = row*256 + (col ^ ((row&7)<<2))
    #pragma unroll
    for (int c = 0; c < 4; ++c) {
        const int col = (wv * 4 + c) * 16 + m;
        const float bv = b1[col];
        #pragma unroll
        for (int rt = 0; rt < 4; ++rt)
            #pragma unroll
            for (int reg = 0; reg < 4; ++reg) {
                const int row = rt * 16 + quad * 4 + reg;   // C/D: row = quad*4+reg
                hid[row * 256 + (col ^ ((row & 7) << 2))] = fmaxf(acc[rt][c][reg] + bv, 0.f);
            }
    }
    __syncthreads();

    // ---- phase 2: logits + softmax. wave wv: rows wv*16+m; quad = h-slice ----
    // R3 BUG FIX: i must run to 8 (i<4 covered only h in [0,128) -> half the
    // hidden sum -> garbage logits -> absmax 1.0). Slices i*32+quad*8+0..7
    // over i=0..7, quad=0..3 tile [0,256) exactly once.
    const int rl = wv * 16 + m;
    const int sw = (rl & 7) << 2;       // row's swizzle
    const float* hrow = hid + rl * 256;
    float lg[NCLS];
    #pragma unroll
    for (int c = 0; c < NCLS; ++c) lg[c] = 0.f;
    #pragma unroll
    for (int i = 0; i < 8; ++i) {
        const int h0 = i * 32 + quad * 8;            // slice: 8 floats per i
        const float4 h1 = *(const float4*)(hrow + (h0 ^ sw));
        const float4 h2 = *(const float4*)(hrow + ((h0 + 4) ^ sw));
        #pragma unroll
        for (int c = 0; c < NCLS; ++c) {
            const float4 wa = *(const float4*)(w2 + c * HID_F + h0);
            const float4 wb = *(const float4*)(w2 + c * HID_F + h0 + 4);
            lg[c] += h1.x * wa.x + h1.y * wa.y + h1.z * wa.z + h1.w * wa.w
                   + h2.x * wb.x + h2.y * wb.y + h2.z * wb.z + h2.w * wb.w;
        }
    }
    #pragma unroll
    for (int c = 0; c < NCLS; ++c) {     // reduce over the 4 quad-slices
        float v = lg[c];
        v += __shfl_xor(v, 16);
        v += __shfl_xor(v, 32);
        lg[c] = v;
    }
    if (quad == 0) {
        float mx = -1e30f;
        #pragma unroll
        for (int c = 0; c < NCLS; ++c) { lg[c] += b2[c]; mx = fmaxf(mx, lg[c]); }
        float s = 0.f;
        #pragma unroll
        for (int c = 0; c < NCLS; ++c) { lg[c] = __expf(lg[c] - mx); s += lg[c]; }
        const float inv = 1.f / s;
        float* o = out + (size_t)(row0 + rl) * NCLS;
        #pragma unroll
        for (int c = 0; c < NCLS; ++c) o[c] = lg[c] * inv;
    }
}

extern "C" void kernel_launch(void* const* d_in, const int* in_sizes, int n_in,
                              void* d_out, int out_size, void* d_ws, size_t ws_size,
                              hipStream_t stream)
{
    const float* x  = (const float*)d_in[0];
    const float* w1 = (const float*)d_in[1];
    const float* b1 = (const float*)d_in[2];
    const float* w2 = (const float*)d_in[3];
    const float* b2 = (const float*)d_in[4];
    float* out = (float*)d_out;

    dim3 grid(BATCH_N / BM);   // 512 blocks = 2 per CU exactly
    dim3 block(NTHREADS);
    hipLaunchKernelGGL(mlp_mfma_kernel, grid, block, 0, stream,
                       x, w1, b1, w2, b2, out);
}

// Round 5
// 218.080 us; speedup vs baseline: 1.5363x; 1.2915x over previous
//
#include <hip/hip_runtime.h>
#include <math.h>

#define BATCH_N   32768
#define IN_F      784
#define HID_F     256
#define NCLS      10
#define BM        64          // batch rows per block
#define BK        32          // K per MFMA step
#define NKT       25          // ceil(784/32), K padded to 800 (pad slots zeroed in prep)
#define NTHREADS  256

typedef __attribute__((ext_vector_type(8))) short short8;  // 8 bf16 = one MFMA operand frag
typedef __attribute__((ext_vector_type(4))) float f32x4;

// d_ws layout: w1 pre-converted to split-bf16 "frag images":
//   slot s = (kt*16 + ct)*64 + lane, 16 B each: B-frag elems j=0..7 =
//   w1[n][k], n = ct*16 + (lane&15), k = kt*32 + (lane>>4)*8 + j  (0 if k>=784)
#define WS_W1H 0
#define WS_W1L 409600          // 25*16*64*16
// total d_ws use: 819200 bytes

union S8U { short8 s; uint4 u; };

// fp32x8 -> split bf16 (hi = truncate, lo = exact residual truncated)
__device__ __forceinline__ void cvt8(float4 a, float4 b, short8* hi, short8* lo) {
    const unsigned M = 0xFFFF0000u;
    const unsigned ux = __float_as_uint(a.x), uy = __float_as_uint(a.y),
                   uz = __float_as_uint(a.z), uw = __float_as_uint(a.w),
                   vx = __float_as_uint(b.x), vy = __float_as_uint(b.y),
                   vz = __float_as_uint(b.z), vw = __float_as_uint(b.w);
    S8U h, l;
    h.u.x = (ux >> 16) | (uy & M);
    h.u.y = (uz >> 16) | (uw & M);
    h.u.z = (vx >> 16) | (vy & M);
    h.u.w = (vz >> 16) | (vw & M);
    const float rx = a.x - __uint_as_float(ux & M);   // exact residuals
    const float ry = a.y - __uint_as_float(uy & M);
    const float rz = a.z - __uint_as_float(uz & M);
    const float rw = a.w - __uint_as_float(uw & M);
    const float sx = b.x - __uint_as_float(vx & M);
    const float sy = b.y - __uint_as_float(vy & M);
    const float sz = b.z - __uint_as_float(vz & M);
    const float sw_ = b.w - __uint_as_float(vw & M);
    l.u.x = (__float_as_uint(rx) >> 16) | (__float_as_uint(ry) & M);
    l.u.y = (__float_as_uint(rz) >> 16) | (__float_as_uint(rw) & M);
    l.u.z = (__float_as_uint(sx) >> 16) | (__float_as_uint(sy) & M);
    l.u.w = (__float_as_uint(sz) >> 16) | (__float_as_uint(sw_) & M);
    *hi = h.s; *lo = l.s;
}

// ---- pre-pass: w1 -> split-bf16 frag images in d_ws (runs every launch) ----
__global__ __launch_bounds__(256)
void prep_w1_kernel(const float* __restrict__ w1, char* __restrict__ ws) {
    const int s    = blockIdx.x * 256 + threadIdx.x;   // 25600 slots
    const int lane = s & 63, ct = (s >> 6) & 15, kt = s >> 10;
    const int n    = ct * 16 + (lane & 15);
    const int k0   = kt * 32 + (lane >> 4) * 8;        // either fully <784 or fully pad
    float4 a = make_float4(0.f, 0.f, 0.f, 0.f), b = a;
    if (k0 + 7 < IN_F) {
        const float* p = w1 + (size_t)n * IN_F + k0;
        a = *(const float4*)p;
        b = *(const float4*)(p + 4);
    }
    short8 hi, lo;
    cvt8(a, b, &hi, &lo);
    *(short8*)(ws + WS_W1H + (size_t)s * 16) = hi;
    *(short8*)(ws + WS_W1L + (size_t)s * 16) = lo;
}

// ---- main: barrier-free K-loop (A: global->reg cvt; B: preconverted frags) ----
__global__ __launch_bounds__(NTHREADS, 2)
void mlp_mfma_kernel(const float* __restrict__ x,
                     const char*  __restrict__ wsb,
                     const float* __restrict__ b1,
                     const float* __restrict__ w2,
                     const float* __restrict__ b2,
                     float* __restrict__ out)
{
    __shared__ float hid[BM * HID_F];   // 64 KB: epilogue only (2 blocks/CU)

    const int tid  = threadIdx.x;
    const int wv   = tid >> 6;          // wave: col-tiles ct = 4wv..4wv+3
    const int lane = tid & 63;
    const int m    = lane & 15;
    const int quad = lane >> 4;
    const int row0 = blockIdx.x * BM;

    f32x4 acc[4][4];
    #pragma unroll
    for (int a = 0; a < 4; ++a)
        #pragma unroll
        for (int b = 0; b < 4; ++b)
            acc[a][b] = (f32x4){0.f, 0.f, 0.f, 0.f};

    // A: lane's frag = x[row0 + rt*16 + m][kb + quad*8 .. +7], contiguous 32B
    const float* xp[4];
    #pragma unroll
    for (int rt = 0; rt < 4; ++rt)
        xp[rt] = x + (size_t)(row0 + rt * 16 + m) * IN_F + quad * 8;

    const char* bhp = wsb + WS_W1H + ((size_t)(wv * 4) * 64 + lane) * 16;
    const char* blp = wsb + WS_W1L + ((size_t)(wv * 4) * 64 + lane) * 16;

    const bool qv = (quad < 2);         // last tile: quads 2,3 are k>=784 (pad)
    #pragma unroll 5
    for (int kt = 0; kt < NKT; ++kt) {
        const int kb = kt * BK;
        const bool valid = (kt < NKT - 1) | qv;   // folds to true for kt<24

        short8 ah[4], al[4], bh[4], bl[4];
        #pragma unroll
        for (int c = 0; c < 4; ++c) {            // B frags: coalesced L2 reads
            bh[c] = *(const short8*)(bhp + (size_t)kt * 16384 + c * 1024);
            bl[c] = *(const short8*)(blp + (size_t)kt * 16384 + c * 1024);
        }
        #pragma unroll
        for (int rt = 0; rt < 4; ++rt) {         // A frags: global -> reg cvt
            float4 a = make_float4(0.f, 0.f, 0.f, 0.f), b4 = a;
            if (valid) {
                a  = *(const float4*)(xp[rt] + kb);
                b4 = *(const float4*)(xp[rt] + kb + 4);
            }
            cvt8(a, b4, &ah[rt], &al[rt]);
        }
        #pragma unroll
        for (int rt = 0; rt < 4; ++rt)
            #pragma unroll
            for (int c = 0; c < 4; ++c) {        // 3-product split-bf16
                acc[rt][c] = __builtin_amdgcn_mfma_f32_16x16x32_bf16(ah[rt], bh[c], acc[rt][c], 0, 0, 0);
                acc[rt][c] = __builtin_amdgcn_mfma_f32_16x16x32_bf16(al[rt], bh[c], acc[rt][c], 0, 0, 0);
                acc[rt][c] = __builtin_amdgcn_mfma_f32_16x16x32_bf16(ah[rt], bl[c], acc[rt][c], 0, 0, 0);
            }
    }

    // ---- epilogue layer 1: bias + relu -> hid (XOR-swizzled) [R4-verified] ----
    #pragma unroll
    for (int c = 0; c < 4; ++c) {
        const int col = (wv * 4 + c) * 16 + m;
        const float bv = b1[col];
        #pragma unroll
        for (int rt = 0; rt < 4; ++rt)
            #pragma unroll
            for (int reg = 0; reg < 4; ++reg) {
                const int row = rt * 16 + quad * 4 + reg;   // C/D: row = quad*4+reg
                hid[row * 256 + (col ^ ((row & 7) << 2))] = fmaxf(acc[rt][c][reg] + bv, 0.f);
            }
    }
    __syncthreads();

    // ---- phase 2: logits + softmax [R4-verified, i<8] ----
    const int rl = wv * 16 + m;
    const int sw = (rl & 7) << 2;
    const float* hrow = hid + rl * 256;
    float lg[NCLS];
    #pragma unroll
    for (int c = 0; c < NCLS; ++c) lg[c] = 0.f;
    #pragma unroll
    for (int i = 0; i < 8; ++i) {
        const int h0 = i * 32 + quad * 8;
        const float4 h1 = *(const float4*)(hrow + (h0 ^ sw));
        const float4 h2 = *(const float4*)(hrow + ((h0 + 4) ^ sw));
        #pragma unroll
        for (int c = 0; c < NCLS; ++c) {
            const float4 wa = *(const float4*)(w2 + c * HID_F + h0);
            const float4 wb = *(const float4*)(w2 + c * HID_F + h0 + 4);
            lg[c] += h1.x * wa.x + h1.y * wa.y + h1.z * wa.z + h1.w * wa.w
                   + h2.x * wb.x + h2.y * wb.y + h2.z * wb.z + h2.w * wb.w;
        }
    }
    #pragma unroll
    for (int c = 0; c < NCLS; ++c) {     // reduce over the 4 quad-slices
        float v = lg[c];
        v += __shfl_xor(v, 16);
        v += __shfl_xor(v, 32);
        lg[c] = v;
    }
    if (quad == 0) {
        float mx = -1e30f;
        #pragma unroll
        for (int c = 0; c < NCLS; ++c) { lg[c] += b2[c]; mx = fmaxf(mx, lg[c]); }
        float s = 0.f;
        #pragma unroll
        for (int c = 0; c < NCLS; ++c) { lg[c] = __expf(lg[c] - mx); s += lg[c]; }
        const float inv = 1.f / s;
        float* o = out + (size_t)(row0 + rl) * NCLS;
        #pragma unroll
        for (int c = 0; c < NCLS; ++c) o[c] = lg[c] * inv;
    }
}

extern "C" void kernel_launch(void* const* d_in, const int* in_sizes, int n_in,
                              void* d_out, int out_size, void* d_ws, size_t ws_size,
                              hipStream_t stream)
{
    const float* x  = (const float*)d_in[0];
    const float* w1 = (const float*)d_in[1];
    const float* b1 = (const float*)d_in[2];
    const float* w2 = (const float*)d_in[3];
    const float* b2 = (const float*)d_in[4];
    float* out = (float*)d_out;

    // pre-pass: w1 -> split-bf16 frag images (25600 slots; runs every call)
    hipLaunchKernelGGL(prep_w1_kernel, dim3(100), dim3(256), 0, stream,
                       w1, (char*)d_ws);
    // main fused MLP
    hipLaunchKernelGGL(mlp_mfma_kernel, dim3(BATCH_N / BM), dim3(NTHREADS), 0, stream,
                       x, (const char*)d_ws, b1, w2, b2, out);
}

// Round 6
// 201.002 us; speedup vs baseline: 1.6668x; 1.0850x over previous
//
#include <hip/hip_runtime.h>
#include <math.h>

#define BATCH_N   32768
#define IN_F      784
#define HID_F     256
#define NCLS      10
#define BM        64          // batch rows per block
#define BK        32          // K per MFMA step
#define NKT       25          // ceil(784/32); kt=24 is the partial tile (peeled)
#define NTHREADS  256

typedef __attribute__((ext_vector_type(8))) short short8;  // 8 bf16 = one MFMA operand frag
typedef __attribute__((ext_vector_type(4))) float f32x4;

// d_ws layout: w1 pre-converted to split-bf16 "frag images":
//   slot s = (kt*16 + ct)*64 + lane, 16 B each: B-frag elems j=0..7 =
//   w1[n][k], n = ct*16 + (lane&15), k = kt*32 + (lane>>4)*8 + j  (0 if k>=784)
#define WS_W1H 0
#define WS_W1L 409600          // 25*16*64*16
// total d_ws use: 819200 bytes

union S8U { short8 s; uint4 u; };

// fp32x8 -> split bf16 (hi = truncate, lo = exact residual truncated)
__device__ __forceinline__ void cvt8(float4 a, float4 b, short8* hi, short8* lo) {
    const unsigned M = 0xFFFF0000u;
    const unsigned ux = __float_as_uint(a.x), uy = __float_as_uint(a.y),
                   uz = __float_as_uint(a.z), uw = __float_as_uint(a.w),
                   vx = __float_as_uint(b.x), vy = __float_as_uint(b.y),
                   vz = __float_as_uint(b.z), vw = __float_as_uint(b.w);
    S8U h, l;
    h.u.x = (ux >> 16) | (uy & M);
    h.u.y = (uz >> 16) | (uw & M);
    h.u.z = (vx >> 16) | (vy & M);
    h.u.w = (vz >> 16) | (vw & M);
    const float rx = a.x - __uint_as_float(ux & M);   // exact residuals
    const float ry = a.y - __uint_as_float(uy & M);
    const float rz = a.z - __uint_as_float(uz & M);
    const float rw = a.w - __uint_as_float(uw & M);
    const float sx = b.x - __uint_as_float(vx & M);
    const float sy = b.y - __uint_as_float(vy & M);
    const float sz = b.z - __uint_as_float(vz & M);
    const float sw_ = b.w - __uint_as_float(vw & M);
    l.u.x = (__float_as_uint(rx) >> 16) | (__float_as_uint(ry) & M);
    l.u.y = (__float_as_uint(rz) >> 16) | (__float_as_uint(rw) & M);
    l.u.z = (__float_as_uint(sx) >> 16) | (__float_as_uint(sy) & M);
    l.u.w = (__float_as_uint(sz) >> 16) | (__float_as_uint(sw_) & M);
    *hi = h.s; *lo = l.s;
}

// ---- pre-pass: w1 -> split-bf16 frag images in d_ws (runs every launch) ----
__global__ __launch_bounds__(256)
void prep_w1_kernel(const float* __restrict__ w1, char* __restrict__ ws) {
    const int s    = blockIdx.x * 256 + threadIdx.x;   // 25600 slots
    const int lane = s & 63, ct = (s >> 6) & 15, kt = s >> 10;
    const int n    = ct * 16 + (lane & 15);
    const int k0   = kt * 32 + (lane >> 4) * 8;        // either fully <784 or fully pad
    float4 a = make_float4(0.f, 0.f, 0.f, 0.f), b = a;
    if (k0 + 7 < IN_F) {
        const float* p = w1 + (size_t)n * IN_F + k0;
        a = *(const float4*)p;
        b = *(const float4*)(p + 4);
    }
    short8 hi, lo;
    cvt8(a, b, &hi, &lo);
    *(short8*)(ws + WS_W1H + (size_t)s * 16) = hi;
    *(short8*)(ws + WS_W1L + (size_t)s * 16) = lo;
}

// ---- main: branch-free, register-pipelined K-loop ----
__global__ __launch_bounds__(NTHREADS, 2)
void mlp_mfma_kernel(const float* __restrict__ x,
                     const char*  __restrict__ wsb,
                     const float* __restrict__ b1,
                     const float* __restrict__ w2,
                     const float* __restrict__ b2,
                     float* __restrict__ out)
{
    __shared__ float hid[BM * HID_F];   // 64 KB: epilogue only (2 blocks/CU)

    const int tid  = threadIdx.x;
    const int wv   = tid >> 6;          // wave: col-tiles ct = 4wv..4wv+3
    const int lane = tid & 63;
    const int m    = lane & 15;
    const int quad = lane >> 4;
    const int row0 = blockIdx.x * BM;
    const int kq   = quad * 8;          // lane's k-offset within a tile

    f32x4 acc[4][4];
    #pragma unroll
    for (int a = 0; a < 4; ++a)
        #pragma unroll
        for (int b = 0; b < 4; ++b)
            acc[a][b] = (f32x4){0.f, 0.f, 0.f, 0.f};

    // A: lane's frag = x[row0 + rt*16 + m][kt*32 + kq .. +7] (32B contiguous)
    const float* xb[4];
    #pragma unroll
    for (int rt = 0; rt < 4; ++rt)
        xb[rt] = x + (size_t)(row0 + rt * 16 + m) * IN_F;

    const char* bhp = wsb + WS_W1H + ((size_t)(wv * 4) * 64 + lane) * 16;
    const char* blp = wsb + WS_W1L + ((size_t)(wv * 4) * 64 + lane) * 16;

    // prologue: load x tile for kt=0 into current regs
    float4 xc[4][2];
    #pragma unroll
    for (int rt = 0; rt < 4; ++rt) {
        xc[rt][0] = *(const float4*)(xb[rt] + kq);
        xc[rt][1] = *(const float4*)(xb[rt] + kq + 4);
    }

    #pragma unroll 4
    for (int kt = 0; kt < NKT - 1; ++kt) {          // kt = 0..23, branch-free
        // B frags for kt (L2-resident, latency covered by cvt + early MFMAs)
        short8 bh[4], bl[4];
        #pragma unroll
        for (int c = 0; c < 4; ++c) {
            bh[c] = *(const short8*)(bhp + (size_t)kt * 16384 + c * 1024);
            bl[c] = *(const short8*)(blp + (size_t)kt * 16384 + c * 1024);
        }
        // prefetch x for kt+1 (clamped so the kt=24 prefetch stays in-bounds;
        // clamp is a no-op for kt+1 < 24)
        int kon = (kt + 1) * BK + kq;
        kon = kon > (IN_F - 8) ? (IN_F - 8) : kon;
        float4 xn[4][2];
        #pragma unroll
        for (int rt = 0; rt < 4; ++rt) {
            xn[rt][0] = *(const float4*)(xb[rt] + kon);
            xn[rt][1] = *(const float4*)(xb[rt] + kon + 4);
        }
        // convert current x to split-bf16 frags (data loaded last iteration)
        short8 ah[4], al[4];
        #pragma unroll
        for (int rt = 0; rt < 4; ++rt)
            cvt8(xc[rt][0], xc[rt][1], &ah[rt], &al[rt]);
        // 3-product split-bf16 MFMA
        #pragma unroll
        for (int rt = 0; rt < 4; ++rt)
            #pragma unroll
            for (int c = 0; c < 4; ++c) {
                acc[rt][c] = __builtin_amdgcn_mfma_f32_16x16x32_bf16(ah[rt], bh[c], acc[rt][c], 0, 0, 0);
                acc[rt][c] = __builtin_amdgcn_mfma_f32_16x16x32_bf16(al[rt], bh[c], acc[rt][c], 0, 0, 0);
                acc[rt][c] = __builtin_amdgcn_mfma_f32_16x16x32_bf16(ah[rt], bl[c], acc[rt][c], 0, 0, 0);
            }
        // rotate (renamed away by unroll-4)
        #pragma unroll
        for (int rt = 0; rt < 4; ++rt) {
            xc[rt][0] = xn[rt][0];
            xc[rt][1] = xn[rt][1];
        }
    }

    // ---- peeled tail kt=24: k in [768,784); quads 2,3 are pad -> zero ----
    {
        const int kt = NKT - 1;
        short8 bh[4], bl[4];
        #pragma unroll
        for (int c = 0; c < 4; ++c) {
            bh[c] = *(const short8*)(bhp + (size_t)kt * 16384 + c * 1024);
            bl[c] = *(const short8*)(blp + (size_t)kt * 16384 + c * 1024);
        }
        short8 ah[4], al[4];
        #pragma unroll
        for (int rt = 0; rt < 4; ++rt)
            cvt8(xc[rt][0], xc[rt][1], &ah[rt], &al[rt]);
        if (quad >= 2) {                 // k >= 784: zero the A frags (once)
            const short8 zz = {0, 0, 0, 0, 0, 0, 0, 0};
            #pragma unroll
            for (int rt = 0; rt < 4; ++rt) { ah[rt] = zz; al[rt] = zz; }
        }
        #pragma unroll
        for (int rt = 0; rt < 4; ++rt)
            #pragma unroll
            for (int c = 0; c < 4; ++c) {
                acc[rt][c] = __builtin_amdgcn_mfma_f32_16x16x32_bf16(ah[rt], bh[c], acc[rt][c], 0, 0, 0);
                acc[rt][c] = __builtin_amdgcn_mfma_f32_16x16x32_bf16(al[rt], bh[c], acc[rt][c], 0, 0, 0);
                acc[rt][c] = __builtin_amdgcn_mfma_f32_16x16x32_bf16(ah[rt], bl[c], acc[rt][c], 0, 0, 0);
            }
    }

    // ---- epilogue layer 1: bias + relu -> hid (XOR-swizzled) [verified] ----
    #pragma unroll
    for (int c = 0; c < 4; ++c) {
        const int col = (wv * 4 + c) * 16 + m;
        const float bv = b1[col];
        #pragma unroll
        for (int rt = 0; rt < 4; ++rt)
            #pragma unroll
            for (int reg = 0; reg < 4; ++reg) {
                const int row = rt * 16 + quad * 4 + reg;   // C/D: row = quad*4+reg
                hid[row * 256 + (col ^ ((row & 7) << 2))] = fmaxf(acc[rt][c][reg] + bv, 0.f);
            }
    }
    __syncthreads();

    // ---- phase 2: logits + softmax [verified, i<8] ----
    const int rl = wv * 16 + m;
    const int sw = (rl & 7) << 2;
    const float* hrow = hid + rl * 256;
    float lg[NCLS];
    #pragma unroll
    for (int c = 0; c < NCLS; ++c) lg[c] = 0.f;
    #pragma unroll
    for (int i = 0; i < 8; ++i) {
        const int h0 = i * 32 + quad * 8;
        const float4 h1 = *(const float4*)(hrow + (h0 ^ sw));
        const float4 h2 = *(const float4*)(hrow + ((h0 + 4) ^ sw));
        #pragma unroll
        for (int c = 0; c < NCLS; ++c) {
            const float4 wa = *(const float4*)(w2 + c * HID_F + h0);
            const float4 wb = *(const float4*)(w2 + c * HID_F + h0 + 4);
            lg[c] += h1.x * wa.x + h1.y * wa.y + h1.z * wa.z + h1.w * wa.w
                   + h2.x * wb.x + h2.y * wb.y + h2.z * wb.z + h2.w * wb.w;
        }
    }
    #pragma unroll
    for (int c = 0; c < NCLS; ++c) {     // reduce over the 4 quad-slices
        float v = lg[c];
        v += __shfl_xor(v, 16);
        v += __shfl_xor(v, 32);
        lg[c] = v;
    }
    if (quad == 0) {
        float mx = -1e30f;
        #pragma unroll
        for (int c = 0; c < NCLS; ++c) { lg[c] += b2[c]; mx = fmaxf(mx, lg[c]); }
        float s = 0.f;
        #pragma unroll
        for (int c = 0; c < NCLS; ++c) { lg[c] = __expf(lg[c] - mx); s += lg[c]; }
        const float inv = 1.f / s;
        float* o = out + (size_t)(row0 + rl) * NCLS;
        #pragma unroll
        for (int c = 0; c < NCLS; ++c) o[c] = lg[c] * inv;
    }
}

extern "C" void kernel_launch(void* const* d_in, const int* in_sizes, int n_in,
                              void* d_out, int out_size, void* d_ws, size_t ws_size,
                              hipStream_t stream)
{
    const float* x  = (const float*)d_in[0];
    const float* w1 = (const float*)d_in[1];
    const float* b1 = (const float*)d_in[2];
    const float* w2 = (const float*)d_in[3];
    const float* b2 = (const float*)d_in[4];
    float* out = (float*)d_out;

    // pre-pass: w1 -> split-bf16 frag images (25600 slots; runs every call)
    hipLaunchKernelGGL(prep_w1_kernel, dim3(100), dim3(256), 0, stream,
                       w1, (char*)d_ws);
    // main fused MLP
    hipLaunchKernelGGL(mlp_mfma_kernel, dim3(BATCH_N / BM), dim3(NTHREADS), 0, stream,
                       x, (const char*)d_ws, b1, w2, b2, out);
}

// Round 7
// 200.243 us; speedup vs baseline: 1.6731x; 1.0038x over previous
//
#include <hip/hip_runtime.h>
#include <math.h>

#define BATCH_N   32768
#define IN_F      784
#define HID_F     256
#define NCLS      10
#define BM        64          // batch rows per block
#define BK        32          // K per MFMA step
#define NKT       25          // ceil(784/32); kt=24 is the partial tile (peeled)
#define NTHREADS  256

typedef __attribute__((ext_vector_type(8))) short short8;  // 8 bf16 = one MFMA operand frag
typedef __attribute__((ext_vector_type(4))) float f32x4;

// d_ws layout: w1 pre-converted to split-bf16 "frag images":
//   slot s = (kt*16 + ct)*64 + lane, 16 B each: B-frag elems j=0..7 =
//   w1[n][k], n = ct*16 + (lane&15), k = kt*32 + (lane>>4)*8 + j  (0 if k>=784)
#define WS_W1H 0
#define WS_W1L 409600          // 25*16*64*16
// total d_ws use: 819200 bytes

union S8U { short8 s; uint4 u; };

// fp32x8 -> split bf16 (hi = truncate, lo = exact residual truncated)
__device__ __forceinline__ void cvt8(float4 a, float4 b, short8* hi, short8* lo) {
    const unsigned M = 0xFFFF0000u;
    const unsigned ux = __float_as_uint(a.x), uy = __float_as_uint(a.y),
                   uz = __float_as_uint(a.z), uw = __float_as_uint(a.w),
                   vx = __float_as_uint(b.x), vy = __float_as_uint(b.y),
                   vz = __float_as_uint(b.z), vw = __float_as_uint(b.w);
    S8U h, l;
    h.u.x = (ux >> 16) | (uy & M);
    h.u.y = (uz >> 16) | (uw & M);
    h.u.z = (vx >> 16) | (vy & M);
    h.u.w = (vz >> 16) | (vw & M);
    const float rx = a.x - __uint_as_float(ux & M);   // exact residuals
    const float ry = a.y - __uint_as_float(uy & M);
    const float rz = a.z - __uint_as_float(uz & M);
    const float rw = a.w - __uint_as_float(uw & M);
    const float sx = b.x - __uint_as_float(vx & M);
    const float sy = b.y - __uint_as_float(vy & M);
    const float sz = b.z - __uint_as_float(vz & M);
    const float sw_ = b.w - __uint_as_float(vw & M);
    l.u.x = (__float_as_uint(rx) >> 16) | (__float_as_uint(ry) & M);
    l.u.y = (__float_as_uint(rz) >> 16) | (__float_as_uint(rw) & M);
    l.u.z = (__float_as_uint(sx) >> 16) | (__float_as_uint(sy) & M);
    l.u.w = (__float_as_uint(sz) >> 16) | (__float_as_uint(sw_) & M);
    *hi = h.s; *lo = l.s;
}

// ---- pre-pass: w1 -> split-bf16 frag images in d_ws (runs every launch) ----
__global__ __launch_bounds__(256)
void prep_w1_kernel(const float* __restrict__ w1, char* __restrict__ ws) {
    const int s    = blockIdx.x * 256 + threadIdx.x;   // 25600 slots
    const int lane = s & 63, ct = (s >> 6) & 15, kt = s >> 10;
    const int n    = ct * 16 + (lane & 15);
    const int k0   = kt * 32 + (lane >> 4) * 8;        // either fully <784 or fully pad
    float4 a = make_float4(0.f, 0.f, 0.f, 0.f), b = a;
    if (k0 + 7 < IN_F) {
        const float* p = w1 + (size_t)n * IN_F + k0;
        a = *(const float4*)p;
        b = *(const float4*)(p + 4);
    }
    short8 hi, lo;
    cvt8(a, b, &hi, &lo);
    *(short8*)(ws + WS_W1H + (size_t)s * 16) = hi;
    *(short8*)(ws + WS_W1L + (size_t)s * 16) = lo;
}

// ---- main: K-loop with explicit register double-buffer on BOTH operands ----
__global__ __launch_bounds__(NTHREADS, 2)
void mlp_mfma_kernel(const float* __restrict__ x,
                     const char*  __restrict__ wsb,
                     const float* __restrict__ b1,
                     const float* __restrict__ w2,
                     const float* __restrict__ b2,
                     float* __restrict__ out)
{
    __shared__ float hid[BM * HID_F];   // 64 KB: epilogue only (2 blocks/CU)

    const int tid  = threadIdx.x;
    const int wv   = tid >> 6;          // wave: col-tiles ct = 4wv..4wv+3
    const int lane = tid & 63;
    const int m    = lane & 15;
    const int quad = lane >> 4;
    const int row0 = blockIdx.x * BM;
    const int kq   = quad * 8;          // lane's k-offset within a tile

    f32x4 acc[4][4];
    #pragma unroll
    for (int a = 0; a < 4; ++a)
        #pragma unroll
        for (int b = 0; b < 4; ++b)
            acc[a][b] = (f32x4){0.f, 0.f, 0.f, 0.f};

    // A: lane's frag = x[row0 + rt*16 + m][kt*32 + kq .. +7] (32B contiguous)
    const float* xb[4];
    #pragma unroll
    for (int rt = 0; rt < 4; ++rt)
        xb[rt] = x + (size_t)(row0 + rt * 16 + m) * IN_F;

    const char* bhp = wsb + WS_W1H + ((size_t)(wv * 4) * 64 + lane) * 16;
    const char* blp = wsb + WS_W1L + ((size_t)(wv * 4) * 64 + lane) * 16;

    // ---- prologue: load kt=0 operands into current buffers ----
    float4 xc[4][2];
    short8 bhc[4], blc[4];
    #pragma unroll
    for (int rt = 0; rt < 4; ++rt) {
        xc[rt][0] = *(const float4*)(xb[rt] + kq);
        xc[rt][1] = *(const float4*)(xb[rt] + kq + 4);
    }
    #pragma unroll
    for (int c = 0; c < 4; ++c) {
        bhc[c] = *(const short8*)(bhp + c * 1024);
        blc[c] = *(const short8*)(blp + c * 1024);
    }

    #pragma unroll 8
    for (int kt = 0; kt < NKT - 1; ++kt) {          // kt = 0..23
        // ---- prefetch kt+1 (B from L2, x from HBM/L3) into next buffers ----
        // x offset clamped so kt=23's prefetch (tile 24, partial) stays
        // in-bounds; clamped lanes (quad>=2) are zeroed in the peeled tail.
        short8 bhn[4], bln[4];
        #pragma unroll
        for (int c = 0; c < 4; ++c) {
            bhn[c] = *(const short8*)(bhp + (size_t)(kt + 1) * 16384 + c * 1024);
            bln[c] = *(const short8*)(blp + (size_t)(kt + 1) * 16384 + c * 1024);
        }
        int kon = (kt + 1) * BK + kq;
        kon = kon > (IN_F - 8) ? (IN_F - 8) : kon;
        float4 xn[4][2];
        #pragma unroll
        for (int rt = 0; rt < 4; ++rt) {
            xn[rt][0] = *(const float4*)(xb[rt] + kon);
            xn[rt][1] = *(const float4*)(xb[rt] + kon + 4);
        }
        // ---- compute kt from CURRENT buffers (loaded >=1 iteration ago) ----
        short8 ah[4], al[4];
        #pragma unroll
        for (int rt = 0; rt < 4; ++rt)
            cvt8(xc[rt][0], xc[rt][1], &ah[rt], &al[rt]);
        #pragma unroll
        for (int rt = 0; rt < 4; ++rt)
            #pragma unroll
            for (int c = 0; c < 4; ++c) {
                acc[rt][c] = __builtin_amdgcn_mfma_f32_16x16x32_bf16(ah[rt], bhc[c], acc[rt][c], 0, 0, 0);
                acc[rt][c] = __builtin_amdgcn_mfma_f32_16x16x32_bf16(al[rt], bhc[c], acc[rt][c], 0, 0, 0);
                acc[rt][c] = __builtin_amdgcn_mfma_f32_16x16x32_bf16(ah[rt], blc[c], acc[rt][c], 0, 0, 0);
            }
        // ---- rotate (renamed away by unroll) ----
        #pragma unroll
        for (int rt = 0; rt < 4; ++rt) {
            xc[rt][0] = xn[rt][0];
            xc[rt][1] = xn[rt][1];
        }
        #pragma unroll
        for (int c = 0; c < 4; ++c) { bhc[c] = bhn[c]; blc[c] = bln[c]; }
    }

    // ---- peeled tail kt=24 (operands already in current buffers) ----
    {
        short8 ah[4], al[4];
        #pragma unroll
        for (int rt = 0; rt < 4; ++rt)
            cvt8(xc[rt][0], xc[rt][1], &ah[rt], &al[rt]);
        if (quad >= 2) {                 // k >= 784: zero the A frags
            const short8 zz = {0, 0, 0, 0, 0, 0, 0, 0};
            #pragma unroll
            for (int rt = 0; rt < 4; ++rt) { ah[rt] = zz; al[rt] = zz; }
        }
        #pragma unroll
        for (int rt = 0; rt < 4; ++rt)
            #pragma unroll
            for (int c = 0; c < 4; ++c) {
                acc[rt][c] = __builtin_amdgcn_mfma_f32_16x16x32_bf16(ah[rt], bhc[c], acc[rt][c], 0, 0, 0);
                acc[rt][c] = __builtin_amdgcn_mfma_f32_16x16x32_bf16(al[rt], bhc[c], acc[rt][c], 0, 0, 0);
                acc[rt][c] = __builtin_amdgcn_mfma_f32_16x16x32_bf16(ah[rt], blc[c], acc[rt][c], 0, 0, 0);
            }
    }

    // ---- epilogue layer 1: bias + relu -> hid (XOR-swizzled) [verified] ----
    #pragma unroll
    for (int c = 0; c < 4; ++c) {
        const int col = (wv * 4 + c) * 16 + m;
        const float bv = b1[col];
        #pragma unroll
        for (int rt = 0; rt < 4; ++rt)
            #pragma unroll
            for (int reg = 0; reg < 4; ++reg) {
                const int row = rt * 16 + quad * 4 + reg;   // C/D: row = quad*4+reg
                hid[row * 256 + (col ^ ((row & 7) << 2))] = fmaxf(acc[rt][c][reg] + bv, 0.f);
            }
    }
    __syncthreads();

    // ---- phase 2: logits + softmax [verified, i<8] ----
    const int rl = wv * 16 + m;
    const int sw = (rl & 7) << 2;
    const float* hrow = hid + rl * 256;
    float lg[NCLS];
    #pragma unroll
    for (int c = 0; c < NCLS; ++c) lg[c] = 0.f;
    #pragma unroll
    for (int i = 0; i < 8; ++i) {
        const int h0 = i * 32 + quad * 8;
        const float4 h1 = *(const float4*)(hrow + (h0 ^ sw));
        const float4 h2 = *(const float4*)(hrow + ((h0 + 4) ^ sw));
        #pragma unroll
        for (int c = 0; c < NCLS; ++c) {
            const float4 wa = *(const float4*)(w2 + c * HID_F + h0);
            const float4 wb = *(const float4*)(w2 + c * HID_F + h0 + 4);
            lg[c] += h1.x * wa.x + h1.y * wa.y + h1.z * wa.z + h1.w * wa.w
                   + h2.x * wb.x + h2.y * wb.y + h2.z * wb.z + h2.w * wb.w;
        }
    }
    #pragma unroll
    for (int c = 0; c < NCLS; ++c) {     // reduce over the 4 quad-slices
        float v = lg[c];
        v += __shfl_xor(v, 16);
        v += __shfl_xor(v, 32);
        lg[c] = v;
    }
    if (quad == 0) {
        float mx = -1e30f;
        #pragma unroll
        for (int c = 0; c < NCLS; ++c) { lg[c] += b2[c]; mx = fmaxf(mx, lg[c]); }
        float s = 0.f;
        #pragma unroll
        for (int c = 0; c < NCLS; ++c) { lg[c] = __expf(lg[c] - mx); s += lg[c]; }
        const float inv = 1.f / s;
        float* o = out + (size_t)(row0 + rl) * NCLS;
        #pragma unroll
        for (int c = 0; c < NCLS; ++c) o[c] = lg[c] * inv;
    }
}

extern "C" void kernel_launch(void* const* d_in, const int* in_sizes, int n_in,
                              void* d_out, int out_size, void* d_ws, size_t ws_size,
                              hipStream_t stream)
{
    const float* x  = (const float*)d_in[0];
    const float* w1 = (const float*)d_in[1];
    const float* b1 = (const float*)d_in[2];
    const float* w2 = (const float*)d_in[3];
    const float* b2 = (const float*)d_in[4];
    float* out = (float*)d_out;

    // pre-pass: w1 -> split-bf16 frag images (25600 slots; runs every call)
    hipLaunchKernelGGL(prep_w1_kernel, dim3(100), dim3(256), 0, stream,
                       w1, (char*)d_ws);
    // main fused MLP
    hipLaunchKernelGGL(mlp_mfma_kernel, dim3(BATCH_N / BM), dim3(NTHREADS), 0, stream,
                       x, (const char*)d_ws, b1, w2, b2, out);
}